// Round 13
// baseline (295.982 us; speedup 1.0000x reference)
//
#include <hip/hip_runtime.h>
#include <hip/hip_cooperative_groups.h>
#include <math.h>

namespace cg = cooperative_groups;

// Problem constants (from reference)
#define BB 32
#define HH 512
#define WW 512
#define T_STEPS 16
#define DT_C 0.2f
#define HW (HH * WW)        // 262144 elements per sample (C=1)
#define RBLK 16             // fallback reduce blocks per sample

// Temporal fusion parameters (NF=8 steps per phase, 2 phases)
#define NF 8
#define TSC 64              // output tile cols
#define TSR 128             // output tile rows
#define ITR 146             // input rows: 24 strips x 6 + 2 static halo rows
#define NSLOT 50            // ROUND-9 slot map (proven): static0 + 24x{top,bot} + static145
#define SLOTW 84            // slot stride in floats

// ---------------------------------------------------------------------------
// Round 1: periodic Laplacian is mean-zero and f<0.25 keeps y in [0,1] ->
//   D = d_coef*sigmoid(mean(x)) is CONSTANT across steps.
// Round 2: no same-address atomics -> deterministic tree reduce.
// Round 3-8: temporal fusion; register-resident 6x8 strips; NF=8 x 2 passes.
// Round 9 (proven 52.8us): slot map top->2s+1, bottom->2s+2, read up 2s /
//   down 2s+3, statics 0/49; IN-LOOP clamp.
// Round 10: __launch_bounds__(256,4) clamped VGPR to 64 -> full spill
//   (WRITE_SIZE 166MB, 7x). Mega kernel CORRECTNESS proven on HW though.
// Rounds 11/12 (clean A/B): clampless inner loop alone = +11us regression
//   (not VALU-bound; likely VGPR/occupancy cliff); slot remap ~neutral.
//   -> keep round-9 inner loop (with clamp) and round-9 slot map EXACTLY.
// Round 13: coop mega with PLAIN __launch_bounds__(256): phase1 load +
//   free register-reduce, grid.sync, phase2 steps+mid write, grid.sync,
//   phase3 remaining steps. Kills reduce pass + 2 launch bubbles. Fallback
//   = exact round-9 3-dispatch pipeline if coop launch fails.
// Validity after k<=8 steps: rows [k,146-k) -> [8,138) >= out [9,137);
//   cols [k,80-k) -> [8,72) == out cols exactly.
// ---------------------------------------------------------------------------

__device__ __forceinline__ float4 clamp4(float4 v) {
    v.x = fminf(fmaxf(v.x, 0.f), 1.f);
    v.y = fminf(fmaxf(v.y, 0.f), 1.f);
    v.z = fminf(fmaxf(v.z, 0.f), 1.f);
    v.w = fminf(fmaxf(v.w, 0.f), 1.f);
    return v;
}

__device__ __forceinline__ float block_sum_256(float v) {
    __shared__ float lds[4];
#pragma unroll
    for (int off = 32; off > 0; off >>= 1)
        v += __shfl_down(v, off, 64);
    const int lane = threadIdx.x & 63;
    const int wid  = threadIdx.x >> 6;
    if (lane == 0) lds[wid] = v;
    __syncthreads();
    float s = 0.f;
    if (threadIdx.x == 0) s = lds[0] + lds[1] + lds[2] + lds[3];
    return s;
}

// Load 6x8 strip into registers + static halo rows + initial publish
// (round-9 slot map). Ends with __syncthreads(). Block-uniform call only.
__device__ __forceinline__ void load_and_publish(
        const float* __restrict__ sb, int h0, int w0, bool act, int s,
        int r1, int cb, float4 cA[6], float4 cB[6], float (*pub)[SLOTW]) {
    const int tid = threadIdx.x;
    const int gc = (w0 - 8 + cb) & (WW - 1);   // 8-aligned, no intra-f4 wrap
#pragma unroll
    for (int j = 0; j < 6; j++) {
        const int gr = (h0 - 9 + r1 + j) & (HH - 1);
        cA[j] = *(const float4*)(sb + gr * WW + gc);
        cB[j] = *(const float4*)(sb + gr * WW + gc + 4);
    }
    if (tid < 40) {   // static halo rows 0 and 145 -> slots 0 and NSLOT-1
        const int r  = tid / 20;
        const int cg = tid % 20;
        const int lr = r ? (ITR - 1) : 0;
        const int gr = (h0 - 9 + lr) & (HH - 1);
        const int gc4 = ((w0 >> 2) - 2 + cg) & (WW / 4 - 1);
        *(float4*)(&pub[r ? (NSLOT - 1) : 0][cg * 4]) =
            *(const float4*)(sb + gr * WW + gc4 * 4);
    }
    if (act) {
        *(float4*)(&pub[2 * s + 1][cb])     = cA[0];
        *(float4*)(&pub[2 * s + 1][cb + 4]) = cB[0];
        *(float4*)(&pub[2 * s + 2][cb])     = cA[5];
        *(float4*)(&pub[2 * s + 2][cb + 4]) = cB[5];
    }
    __syncthreads();
}

// nst Euler steps, register-resident with up-carry, ROUND-9 arithmetic
// (in-loop clamp -- clampless regressed, see rounds 11/12).
__device__ __forceinline__ void do_steps(
        int nst, float f, bool act, int s, int cb,
        float4 cA[6], float4 cB[6], float (*pub)[SLOTW]) {
    for (int it = 0; it < nst; it++) {
        float4 uA = *(const float4*)(&pub[2 * s][cb]);       // bottom(s-1)
        float4 uB = *(const float4*)(&pub[2 * s][cb + 4]);
        const float4 dA = *(const float4*)(&pub[2 * s + 3][cb]);  // top(s+1)
        const float4 dB = *(const float4*)(&pub[2 * s + 3][cb + 4]);
#pragma unroll
        for (int j = 0; j < 6; j++) {
            const float4 a = cA[j];
            const float4 q = cB[j];
            const float4 nA = (j == 5) ? dA : cA[j + 1];
            const float4 nB = (j == 5) ? dB : cB[j + 1];
            const float L = __shfl_up(q.w, 1, 64);    // lane-1's col cb-1
            const float R = __shfl_down(a.x, 1, 64);  // lane+1's col cb+8
            float4 oA, oB;
            oA.x = fmaf(f, L   + a.y + uA.x + nA.x - 4.f * a.x, a.x);
            oA.y = fmaf(f, a.x + a.z + uA.y + nA.y - 4.f * a.y, a.y);
            oA.z = fmaf(f, a.y + a.w + uA.z + nA.z - 4.f * a.z, a.z);
            oA.w = fmaf(f, a.z + q.x + uA.w + nA.w - 4.f * a.w, a.w);
            oB.x = fmaf(f, a.w + q.y + uB.x + nB.x - 4.f * q.x, q.x);
            oB.y = fmaf(f, q.x + q.z + uB.y + nB.y - 4.f * q.y, q.y);
            oB.z = fmaf(f, q.y + q.w + uB.z + nB.z - 4.f * q.z, q.z);
            oB.w = fmaf(f, q.z + R   + uB.w + nB.w - 4.f * q.w, q.w);
            cA[j] = clamp4(oA);
            cB[j] = clamp4(oB);
            uA = a;
            uB = q;
        }
        __syncthreads();    // halo reads of this step complete
        if (act) {
            *(float4*)(&pub[2 * s + 1][cb])     = cA[0];
            *(float4*)(&pub[2 * s + 1][cb + 4]) = cB[0];
            *(float4*)(&pub[2 * s + 2][cb])     = cA[5];
            *(float4*)(&pub[2 * s + 2][cb + 4]) = cB[5];
        }
        __syncthreads();    // halo writes visible for next step
    }
}

// Write exclusive region: local rows [9,137), col groups 1..8 (values are
// already clamped by the in-loop clamp).
__device__ __forceinline__ void write_tile(
        float* __restrict__ db, int h0, int w0, bool act, int g, int r1,
        int cb, const float4 cA[6], const float4 cB[6]) {
    if (act && g >= 1 && g < 9) {
        const int gcol = w0 - 8 + cb;
#pragma unroll
        for (int j = 0; j < 6; j++) {
            const int lr = r1 + j;
            if (lr >= 9 && lr < 137) {
                float* p = db + (size_t)(h0 + lr - 9) * WW + gcol;
                *(float4*)p       = cA[j];
                *(float4*)(p + 4) = cB[j];
            }
        }
    }
}

// ---------------- cooperative mega kernel: everything in one launch --------
// grid: 1024 = 32 samples x 32 tiles (8 col x 4 row). block: 256.
// PLAIN launch bounds: let the allocator pick VGPR (round-10 lesson).
__global__ __launch_bounds__(256) void mega_kernel(
        const float* __restrict__ x, float* __restrict__ f1,
        float* __restrict__ out, const int* __restrict__ t,
        const float* __restrict__ dcoef, float* __restrict__ partials) {
    cg::grid_group grid = cg::this_grid();
    const int bid  = blockIdx.x;
    const int b    = bid >> 5;
    const int tile = bid & 31;
    const int tx = tile & 7, ty = tile >> 3;
    const int h0 = ty * TSR, w0 = tx * TSC;
    const int tb = t[b];
    const int tid = threadIdx.x;

    // lane mapping: 6 strips x 10 col-groups per wave; lanes 60-63 duplicate
    // strip 0 so every shfl source is deterministic (garbage stays in halo).
    const int ln  = tid & 63;
    const int si  = ln / 10;
    const int g   = ln - si * 10;
    const bool act = (si < 6);
    const int s   = act ? ((tid >> 6) * 6 + si) : 0;
    const int r1  = 1 + 6 * s;
    const int cb  = 8 * (act ? g : 0);

    __shared__ __align__(16) float pub[NSLOT][SLOTW];
    float4 cA[6], cB[6];

    // ---- phase 1: load (+free partial reduce) or t==0 copy ----
    if (tb == 0) {
        const float4* s4 = (const float4*)(x + (size_t)b * HW);
        float4* d4 = (float4*)(out + (size_t)b * HW);
        for (int j = tid; j < TSR * (TSC / 4); j += 256) {
            const int r = j >> 4, c4 = j & 15;
            const int idx = (h0 + r) * (WW / 4) + (w0 >> 2) + c4;
            d4[idx] = clamp4(s4[idx]);
        }
    } else {
        load_and_publish(x + (size_t)b * HW, h0, w0, act, s, r1, cb, cA, cB, pub);
        // partial sum over this tile's exclusive 64x128 region (from regs)
        float ps = 0.f;
        if (act && g >= 1 && g < 9) {
#pragma unroll
            for (int j = 0; j < 6; j++) {
                const int lr = r1 + j;
                if (lr >= 9 && lr < 137)
                    ps += ((cA[j].x + cA[j].y) + (cA[j].z + cA[j].w))
                        + ((cB[j].x + cB[j].y) + (cB[j].z + cB[j].w));
            }
        }
        const float bs = block_sum_256(ps);
        if (tid == 0) partials[bid] = bs;
    }

    grid.sync();

    // ---- phase 2: f from partials; steps 1..min(tb,8); mid write ----
    float f = 0.f;
    if (tb > 0) {
        float psum = 0.f;
#pragma unroll
        for (int k = 0; k < 32; k++) psum += partials[(b << 5) + k];
        f = dcoef[0] * (1.0f / (1.0f + expf(-psum * (1.0f / (float)HW)))) * DT_C;
        const int nst = (tb > NF) ? NF : tb;
        do_steps(nst, f, act, s, cb, cA, cB, pub);
        write_tile((tb <= NF ? out : f1) + (size_t)b * HW,
                   h0, w0, act, g, r1, cb, cA, cB);
    }

    grid.sync();

    // ---- phase 3: remaining steps for t>8 samples ----
    if (tb > NF) {
        load_and_publish(f1 + (size_t)b * HW, h0, w0, act, s, r1, cb, cA, cB, pub);
        do_steps(tb - NF, f, act, s, cb, cA, cB, pub);
        write_tile(out + (size_t)b * HW, h0, w0, act, g, r1, cb, cA, cB);
    }
}

// ---------------- fallback path (exact round-9 structure, proven) ----------
__global__ __launch_bounds__(256) void reduce_x_kernel(
        const float* __restrict__ x, const int* __restrict__ t,
        float* __restrict__ partials) {
    const int b = blockIdx.y;
    if (t[b] <= 0) return;
    const float4* xb = (const float4*)(x + (size_t)b * HW);
    float v = 0.f;
    const int base = blockIdx.x * (HW / 4 / RBLK);
#pragma unroll
    for (int k = 0; k < 16; k++) {
        float4 c = xb[base + k * 256 + threadIdx.x];
        v += (c.x + c.y) + (c.z + c.w);
    }
    float s = block_sum_256(v);
    if (threadIdx.x == 0) partials[b * RBLK + blockIdx.x] = s;
}

__global__ __launch_bounds__(256) void fused_kernel(
        const float* __restrict__ src, float* __restrict__ adst,
        float* __restrict__ fdst, const float* __restrict__ x,
        float* __restrict__ out, const int* __restrict__ t,
        const float* __restrict__ partials, const float* __restrict__ dcoef,
        int base) {
    const int b = blockIdx.y;
    const int tb = t[b];
    const int tx = blockIdx.x & 7;
    const int ty = blockIdx.x >> 3;
    const int h0 = ty * TSR;
    const int w0 = tx * TSC;

    if (tb <= base) {
        if (base == 0 && tb == 0) {
            const float4* s4 = (const float4*)(x + (size_t)b * HW);
            float4* d4 = (float4*)(out + (size_t)b * HW);
            for (int j = threadIdx.x; j < TSR * (TSC / 4); j += 256) {
                const int r = j >> 4, c4 = j & 15;
                const int idx = (h0 + r) * (WW / 4) + (w0 >> 2) + c4;
                d4[idx] = clamp4(s4[idx]);
            }
        }
        return;
    }

    int nst = tb - base;
    if (nst > NF) nst = NF;
    float* dstp = (tb <= base + NF) ? fdst : adst;

    float psum = 0.f;
#pragma unroll
    for (int k = 0; k < RBLK; k++) psum += partials[b * RBLK + k];
    const float f = dcoef[0] * (1.0f / (1.0f + expf(-psum * (1.0f / (float)HW)))) * DT_C;

    __shared__ __align__(16) float pub[NSLOT][SLOTW];

    const int ln  = threadIdx.x & 63;
    const int si  = ln / 10;
    const int g   = ln - si * 10;
    const bool act = (si < 6);
    const int s   = act ? ((threadIdx.x >> 6) * 6 + si) : 0;
    const int r1  = 1 + 6 * s;
    const int cb  = 8 * (act ? g : 0);

    float4 cA[6], cB[6];
    load_and_publish(src + (size_t)b * HW, h0, w0, act, s, r1, cb, cA, cB, pub);
    do_steps(nst, f, act, s, cb, cA, cB, pub);
    write_tile(dstp + (size_t)b * HW, h0, w0, act, g, r1, cb, cA, cB);
}

extern "C" void kernel_launch(void* const* d_in, const int* in_sizes, int n_in,
                              void* d_out, int out_size, void* d_ws, size_t ws_size,
                              hipStream_t stream) {
    const float* x     = (const float*)d_in[0];
    const int*   t     = (const int*)d_in[1];
    const float* dcoef = (const float*)d_in[2];
    float* out = (float*)d_out;

    // ws layout (header 4 KiB): [partials: 1024 floats][f1 @ 4 KiB: 32 MiB]
    float* partials = (float*)d_ws;
    float* f1       = (float*)((char*)d_ws + 4096);

    void* args[6];
    args[0] = (void*)&x;
    args[1] = (void*)&f1;
    args[2] = (void*)&out;
    args[3] = (void*)&t;
    args[4] = (void*)&dcoef;
    args[5] = (void*)&partials;
    hipError_t e = hipLaunchCooperativeKernel((const void*)mega_kernel,
                                              dim3(BB * 32), dim3(256),
                                              args, 0, stream);
    if (e != hipSuccess) {
        // deterministic fallback: exact round-9 3-dispatch pipeline
        (void)hipGetLastError();
        reduce_x_kernel<<<dim3(RBLK, BB), dim3(256), 0, stream>>>(x, t, partials);
        fused_kernel<<<dim3(32, BB), dim3(256), 0, stream>>>(x,  f1, out, x, out, t, partials, dcoef, 0);
        fused_kernel<<<dim3(32, BB), dim3(256), 0, stream>>>(f1, f1, out, x, out, t, partials, dcoef, 8);
    }
}

// Round 14
// 52.635 us; speedup vs baseline: 5.6233x; 5.6233x over previous
//
#include <hip/hip_runtime.h>
#include <math.h>

// Problem constants (from reference)
#define BB 32
#define HH 512
#define WW 512
#define T_STEPS 16
#define DT_C 0.2f
#define HW (HH * WW)        // 262144 elements per sample (C=1)
#define RBLK 16             // reduce blocks per sample

// Temporal fusion parameters (NF=8 steps per dispatch, 2 dispatches)
#define NF 8
#define TSC 64              // output tile cols
#define TSR 128             // output tile rows
#define ITR 146             // input rows: 24 strips x 6 + 2 static halo rows
#define ITC 80              // input cols (halo 8 left, 8 right)
#define NSLOT 50            // LDS publish rows: static0 + 24x{top,bot} + static145
#define SLOTW 84            // LDS slot stride in floats

// ---------------------------------------------------------------------------
// PROVEN 52.8us CONFIGURATION (round 9) - restored byte-exact after rounds
// 10-13 all regressed. Change log of refuted alternatives:
//   R10: coop mega + __launch_bounds__(256,4): VGPR clamped to 64 -> full
//        strip spill (WRITE_SIZE 166MB), 389us.
//   R11: clampless + slot remap bundle: 62us.
//   R12: clampless alone: 64us (NOT VALU-bound; clamp version faster --
//        likely shorter live ranges / better scheduling).
//   R13: coop mega + plain bounds: VGPR=52 anyway (grid.sync ABI + state
//        live across sync forces spill), 296us. Coop approach abandoned.
// Design facts:
//   - Periodic Laplacian is mean-zero, f<0.25 -> y stays in [0,1], clip is
//     a no-op mid-run -> D = d_coef*sigmoid(mean(x)) CONSTANT across steps.
//   - Two-stage deterministic reduce (no same-address atomics; R2 lesson).
//   - 2 fused dispatches x NF=8 steps, chain x -> f1 -> out; finishing
//     samples always write out (src never aliases out; R4 lesson).
//   - Register-resident 6-row x 8-col strips; LDS = 50-slot publish buffer;
//     slot map: top(s)->2s+1, bottom(s)->2s+2, read up from 2s, down from
//     2s+3, statics at 0/49.
//   - Validity after k<=8 steps: rows [k,146-k) -> [8,138) >= out [9,137);
//     cols [k,80-k) -> [8,72) == out cols exactly.
// ---------------------------------------------------------------------------

__device__ __forceinline__ float block_sum_256(float v) {
    __shared__ float lds[4];
#pragma unroll
    for (int off = 32; off > 0; off >>= 1)
        v += __shfl_down(v, off, 64);
    const int lane = threadIdx.x & 63;
    const int wid  = threadIdx.x >> 6;
    if (lane == 0) lds[wid] = v;
    __syncthreads();
    float s = 0.f;
    if (threadIdx.x == 0) s = lds[0] + lds[1] + lds[2] + lds[3];
    return s;
}

// Stage 1: per-block partial sums of x. grid: (RBLK, BB), block: 256.
__global__ __launch_bounds__(256) void reduce_x_kernel(
        const float* __restrict__ x, const int* __restrict__ t,
        float* __restrict__ partials) {
    const int b = blockIdx.y;
    if (t[b] <= 0) return;                 // D unused for t==0 samples
    const float4* xb = (const float4*)(x + (size_t)b * HW);
    float v = 0.f;
    const int base = blockIdx.x * (HW / 4 / RBLK);   // 4096 float4 per block
#pragma unroll
    for (int k = 0; k < 16; k++) {
        float4 c = xb[base + k * 256 + threadIdx.x];
        v += (c.x + c.y) + (c.z + c.w);
    }
    float s = block_sum_256(v);
    if (threadIdx.x == 0) partials[b * RBLK + blockIdx.x] = s;
}

__device__ __forceinline__ float4 clamp4(float4 v) {
    v.x = fminf(fmaxf(v.x, 0.f), 1.f);
    v.y = fminf(fmaxf(v.y, 0.f), 1.f);
    v.z = fminf(fmaxf(v.z, 0.f), 1.f);
    v.w = fminf(fmaxf(v.w, 0.f), 1.f);
    return v;
}

// Fused kernel: up to NF Euler steps, field register-resident (6-row x 8-col
// per thread). grid: (32, BB) -- 8 col-tiles x 4 row-tiles. block: 256.
__global__ __launch_bounds__(256) void fused_kernel(
        const float* __restrict__ src,   // stencil source buffer
        float* __restrict__ adst,        // destination: still-active samples
        float* __restrict__ fdst,        // destination: finishing samples (== out)
        const float* __restrict__ x,     // original input (t==0 copy, base==0)
        float* __restrict__ out,         // final output (t==0 copy dest)
        const int* __restrict__ t,
        const float* __restrict__ partials,
        const float* __restrict__ dcoef,
        int base) {
    const int b = blockIdx.y;
    const int tb = t[b];
    const int tx = blockIdx.x & 7;       // col tile 0..7
    const int ty = blockIdx.x >> 3;      // row tile 0..3
    const int h0 = ty * TSR;
    const int w0 = tx * TSC;

    if (tb <= base) {
        if (base == 0 && tb == 0) {
            // copy x -> out (clip applied; near-no-op on [0,1) input)
            const float4* s4 = (const float4*)(x + (size_t)b * HW);
            float4* d4 = (float4*)(out + (size_t)b * HW);
            for (int j = threadIdx.x; j < TSR * (TSC / 4); j += 256) {
                const int r = j >> 4, c4 = j & 15;
                const int idx = (h0 + r) * (WW / 4) + (w0 >> 2) + c4;
                d4[idx] = clamp4(s4[idx]);
            }
        }
        return;   // sample finished earlier; data already in out
    }

    int nst = tb - base;
    if (nst > NF) nst = NF;
    float* dstp = (tb <= base + NF) ? fdst : adst;

    // f computed inline (block-uniform, deterministic sequential sum)
    float psum = 0.f;
#pragma unroll
    for (int k = 0; k < RBLK; k++) psum += partials[b * RBLK + k];
    const float f = dcoef[0] * (1.0f / (1.0f + expf(-psum * (1.0f / (float)HW)))) * DT_C;

    __shared__ __align__(16) float pub[NSLOT][SLOTW];

    // ---- lane mapping: 6 strips x 10 col-groups per wave ----
    const int ln  = threadIdx.x & 63;
    const int si  = ln / 10;                 // 0..5 active, 6 = idle-duplicate
    const int g   = ln - si * 10;            // 8-col group 0..9 (0..3 for si=6)
    const bool act = (si < 6);
    const int s   = act ? ((threadIdx.x >> 6) * 6 + si) : 0;  // strip 0..23
    const int r1  = 1 + 6 * s;               // first owned local row
    const int cb  = 8 * (act ? g : 0);       // local col base 0..72

    const float* sb = src + (size_t)b * HW;
    const int gc = (w0 - 8 + cb) & (WW - 1); // global col base (8-aligned)

    // ---- load 6 rows x 8 cols straight into registers ----
    float4 cA[6], cB[6];
#pragma unroll
    for (int j = 0; j < 6; j++) {
        const int gr = (h0 - 9 + r1 + j) & (HH - 1);
        cA[j] = *(const float4*)(sb + gr * WW + gc);
        cB[j] = *(const float4*)(sb + gr * WW + gc + 4);
    }
    // static halo rows 0 and 145 -> slots 0 and NSLOT-1
    if (threadIdx.x < 40) {
        const int r  = threadIdx.x / 20;     // 0: top halo, 1: bottom halo
        const int cg = threadIdx.x % 20;
        const int lr = r ? (ITR - 1) : 0;
        const int gr = (h0 - 9 + lr) & (HH - 1);
        const int gc4 = ((w0 >> 2) - 2 + cg) & (WW / 4 - 1);
        *(float4*)(&pub[r ? (NSLOT - 1) : 0][cg * 4]) =
            *(const float4*)(sb + gr * WW + gc4 * 4);
    }
    // initial publish of strip top/bottom: top->2s+1, bottom->2s+2
    if (act) {
        *(float4*)(&pub[2 * s + 1][cb])     = cA[0];
        *(float4*)(&pub[2 * s + 1][cb + 4]) = cB[0];
        *(float4*)(&pub[2 * s + 2][cb])     = cA[5];
        *(float4*)(&pub[2 * s + 2][cb + 4]) = cB[5];
    }
    __syncthreads();

    // ---- nst register-resident Euler steps (up-carry, in-loop clamp) ----
    for (int it = 0; it < nst; it++) {
        float4 uA = *(const float4*)(&pub[2 * s][cb]);       // bottom(s-1)
        float4 uB = *(const float4*)(&pub[2 * s][cb + 4]);
        const float4 dA = *(const float4*)(&pub[2 * s + 3][cb]);  // top(s+1)
        const float4 dB = *(const float4*)(&pub[2 * s + 3][cb + 4]);
#pragma unroll
        for (int j = 0; j < 6; j++) {
            const float4 a = cA[j];
            const float4 q = cB[j];
            const float4 nA = (j == 5) ? dA : cA[j + 1];
            const float4 nB = (j == 5) ? dB : cB[j + 1];
            const float L = __shfl_up(q.w, 1, 64);    // lane-1's col cb-1
            const float R = __shfl_down(a.x, 1, 64);  // lane+1's col cb+8
            float4 oA, oB;
            oA.x = fmaf(f, L   + a.y + uA.x + nA.x - 4.f * a.x, a.x);
            oA.y = fmaf(f, a.x + a.z + uA.y + nA.y - 4.f * a.y, a.y);
            oA.z = fmaf(f, a.y + a.w + uA.z + nA.z - 4.f * a.z, a.z);
            oA.w = fmaf(f, a.z + q.x + uA.w + nA.w - 4.f * a.w, a.w);
            oB.x = fmaf(f, a.w + q.y + uB.x + nB.x - 4.f * q.x, q.x);
            oB.y = fmaf(f, q.x + q.z + uB.y + nB.y - 4.f * q.y, q.y);
            oB.z = fmaf(f, q.y + q.w + uB.z + nB.z - 4.f * q.z, q.z);
            oB.w = fmaf(f, q.z + R   + uB.w + nB.w - 4.f * q.w, q.w);
            cA[j] = clamp4(oA);
            cB[j] = clamp4(oB);
            uA = a;
            uB = q;
        }
        __syncthreads();    // halo reads of this step complete
        if (act) {
            *(float4*)(&pub[2 * s + 1][cb])     = cA[0];
            *(float4*)(&pub[2 * s + 1][cb + 4]) = cB[0];
            *(float4*)(&pub[2 * s + 2][cb])     = cA[5];
            *(float4*)(&pub[2 * s + 2][cb + 4]) = cB[5];
        }
        __syncthreads();    // halo writes visible for next step
    }

    // ---- write output: local rows [9,137), col groups 1..8 ----
    if (act && g >= 1 && g < 9) {
        float* db = dstp + (size_t)b * HW;
        const int gcol = w0 - 8 + cb;        // in [w0, w0+56]
#pragma unroll
        for (int j = 0; j < 6; j++) {
            const int lr = r1 + j;
            if (lr >= 9 && lr < 137) {
                float* p = db + (size_t)(h0 + lr - 9) * WW + gcol;
                *(float4*)p       = cA[j];
                *(float4*)(p + 4) = cB[j];
            }
        }
    }
}

extern "C" void kernel_launch(void* const* d_in, const int* in_sizes, int n_in,
                              void* d_out, int out_size, void* d_ws, size_t ws_size,
                              hipStream_t stream) {
    const float* x     = (const float*)d_in[0];
    const int*   t     = (const int*)d_in[1];
    const float* dcoef = (const float*)d_in[2];
    float* out = (float*)d_out;

    // ws layout (header 4 KiB): [partials: 32*16 floats][f1 @ 4 KiB: 32 MiB]
    float* partials = (float*)d_ws;
    float* f1       = (float*)((char*)d_ws + 4096);

    reduce_x_kernel<<<dim3(RBLK, BB), dim3(256), 0, stream>>>(x, t, partials);

    // Chain x -> f1 -> out; finishing samples always write out
    // (src never aliases out -> no hazard, no fix-up pass).
    fused_kernel<<<dim3(32, BB), dim3(256), 0, stream>>>(x,  f1, out, x, out, t, partials, dcoef, 0);
    fused_kernel<<<dim3(32, BB), dim3(256), 0, stream>>>(f1, f1, out, x, out, t, partials, dcoef, 8);
}